// Round 1
// baseline (194.039 us; speedup 1.0000x reference)
//
#include <hip/hip_runtime.h>

#define NV 4096
#define NF 2048
#define ISZ 256
#define OSZ 128
#define TILE 16
#define CHUNK 256
#define FAR_P 100.0f
#define NEAR_P 0.1f

// ---------------- kernel 1: project vertices ----------------
__global__ __launch_bounds__(256) void proj_kernel(
    const float* __restrict__ verts, const float* __restrict__ Km,
    const float* __restrict__ Rm, const float* __restrict__ tv,
    const float* __restrict__ dc, float4* __restrict__ pv)
{
    int i = blockIdx.x * 256 + threadIdx.x;
    if (i >= NV) return;
    float x = verts[3*i+0], y = verts[3*i+1], z = verts[3*i+2];
    // v = R*[x,y,z] + t   (einsum 'bvj,bij->bvi')
    float vx = x*Rm[0] + y*Rm[1] + z*Rm[2] + tv[0];
    float vy = x*Rm[3] + y*Rm[4] + z*Rm[5] + tv[1];
    float vz = x*Rm[6] + y*Rm[7] + z*Rm[8] + tv[2];
    float zd = vz + 1e-5f;
    float x_ = vx / zd;
    float y_ = vy / zd;
    float r2 = x_*x_ + y_*y_;
    float k1 = dc[0], k2 = dc[1], p1 = dc[2], p2 = dc[3], k3 = dc[4];
    float radial = 1.0f + k1*r2 + k2*r2*r2 + k3*r2*r2*r2;
    float x__ = x_*radial + 2.0f*p1*x_*y_ + p2*(r2 + 2.0f*x_*x_);
    float y__ = y_*radial + p1*(r2 + 2.0f*y_*y_) + 2.0f*p2*x_*y_;
    float u  = x__*Km[0] + y__*Km[1] + Km[2];
    float vv = x__*Km[3] + y__*Km[4] + Km[5];
    vv = 1024.0f - vv;
    u  = 2.0f*(u  - 512.0f) / 1024.0f;
    vv = 2.0f*(vv - 512.0f) / 1024.0f;
    pv[i] = make_float4(u, vv, vz, 1.0f / vz);
}

// ---------------- kernel 2: per-face setup ----------------
// layout per face (4 x float4):
//   q0 = (X0, Y0, X1, Y1)
//   q1 = (X2, Y2, RZ0, RZ1)
//   q2 = (RZ2, minx, maxx, miny)
//   q3 = (maxy, -, -, -)
__global__ __launch_bounds__(256) void setup_kernel(
    const int* __restrict__ faces, const float4* __restrict__ pv,
    float4* __restrict__ tri)
{
    int f = blockIdx.x * 256 + threadIdx.x;
    if (f >= NF) return;
    int i0 = faces[3*f+0], i1 = faces[3*f+1], i2 = faces[3*f+2];
    float4 p0 = pv[i0], p1 = pv[i1], p2 = pv[i2];
    // pad bbox by 1e-4 (<< pixel pitch 7.8e-3) to absorb fp rounding at edges
    float minx = fminf(p0.x, fminf(p1.x, p2.x)) - 1e-4f;
    float maxx = fmaxf(p0.x, fmaxf(p1.x, p2.x)) + 1e-4f;
    float miny = fminf(p0.y, fminf(p1.y, p2.y)) - 1e-4f;
    float maxy = fmaxf(p0.y, fmaxf(p1.y, p2.y)) + 1e-4f;
    tri[4*f+0] = make_float4(p0.x, p0.y, p1.x, p1.y);
    tri[4*f+1] = make_float4(p2.x, p2.y, p0.w, p1.w);
    tri[4*f+2] = make_float4(p2.w, minx, maxx, miny);
    tri[4*f+3] = make_float4(maxy, 0.0f, 0.0f, 0.0f);
}

// ---------------- kernel 3: tiled rasterizer ----------------
__global__ __launch_bounds__(256) void raster_kernel(
    const float4* __restrict__ tri, float* __restrict__ out)
{
    __shared__ float4 s_tri[CHUNK*4];
    __shared__ unsigned short s_list[CHUNK];
    __shared__ int s_cnt;
    __shared__ float s_z[TILE][TILE];

    const int tid = threadIdx.x;
    const int tx = tid & 15, ty = tid >> 4;
    const int tileX = blockIdx.x, tileY = blockIdx.y;
    const int px = tileX*TILE + tx, py = tileY*TILE + ty;

    // reference pixel centers: xs=(2i+1-256)/256, ys=(2(255-j)+1-256)/256
    const float xp = (2.0f*(float)px + 1.0f - 256.0f) * (1.0f/256.0f);
    const float yp = (2.0f*(float)(255 - py) + 1.0f - 256.0f) * (1.0f/256.0f);

    // tile NDC bounds
    const float tbx0 = (2.0f*(float)(tileX*TILE)          + 1.0f - 256.0f) * (1.0f/256.0f);
    const float tbx1 = (2.0f*(float)(tileX*TILE + TILE-1) + 1.0f - 256.0f) * (1.0f/256.0f);
    const float tby1 = (2.0f*(float)(255 - tileY*TILE)           + 1.0f - 256.0f) * (1.0f/256.0f);
    const float tby0 = (2.0f*(float)(255 - (tileY*TILE+TILE-1))  + 1.0f - 256.0f) * (1.0f/256.0f);

    const int lane = tid & 63;
    float zmin = FAR_P;

    for (int base = 0; base < NF; base += CHUNK) {
        __syncthreads();   // previous iteration readers done before restage
        #pragma unroll
        for (int k = 0; k < 4; ++k)
            s_tri[k*CHUNK + tid] = tri[base*4 + k*CHUNK + tid];
        if (tid == 0) s_cnt = 0;
        __syncthreads();

        // bbox vs tile: thread tid tests triangle tid of the chunk
        float4 q2 = s_tri[tid*4+2];
        float  maxy = s_tri[tid*4+3].x;
        bool hit = (q2.y <= tbx1) && (q2.z >= tbx0) && (q2.w <= tby1) && (maxy >= tby0);

        unsigned long long m = __ballot(hit);
        int wbase = 0;
        if (lane == 0 && m) wbase = atomicAdd(&s_cnt, (int)__popcll(m));
        wbase = __shfl(wbase, 0, 64);
        if (hit) {
            int pos = wbase + (int)__popcll(m & ((1ull << lane) - 1ull));
            s_list[pos] = (unsigned short)tid;
        }
        __syncthreads();

        const int cnt = s_cnt;
        for (int k = 0; k < cnt; ++k) {
            int j = s_list[k];
            float4 q0 = s_tri[j*4+0];
            float4 q1 = s_tri[j*4+1];
            float4 qq = s_tri[j*4+2];
            // reference-exact edge functions
            float dx0 = q0.x - xp, dy0 = q0.y - yp;
            float dx1 = q0.z - xp, dy1 = q0.w - yp;
            float dx2 = q1.x - xp, dy2 = q1.y - yp;
            float w0 = dx1*dy2 - dx2*dy1;
            float w1 = dx2*dy0 - dx0*dy2;
            float w2 = dx0*dy1 - dx1*dy0;
            float area = (w0 + w1) + w2;
            bool  ok   = fabsf(area) > 1e-10f;
            float inv  = __builtin_amdgcn_rcpf(ok ? area : 1.0f);
            float b0 = w0*inv, b1 = w1*inv, b2 = w2*inv;
            bool inside = ok && (b0 >= 0.0f) && (b1 >= 0.0f) && (b2 >= 0.0f);
            float zinv = b0*q1.z + b1*q1.w + b2*qq.x;
            float zz = (fabsf(zinv) > 1e-10f) ? __builtin_amdgcn_rcpf(zinv) : 1.0f;
            bool valid = inside && (zz > NEAR_P) && (zz < FAR_P);
            zmin = fminf(zmin, valid ? zz : FAR_P);
        }
    }

    // 2x2 AA mean-pool inside the block
    __syncthreads();
    s_z[ty][tx] = zmin;
    __syncthreads();
    if (tx < 8 && ty < 8) {
        float m4 = ((s_z[2*ty][2*tx]   + s_z[2*ty][2*tx+1]) +
                    (s_z[2*ty+1][2*tx] + s_z[2*ty+1][2*tx+1])) * 0.25f;
        out[(tileY*8 + ty)*OSZ + (tileX*8 + tx)] = m4;
    }
}

extern "C" void kernel_launch(void* const* d_in, const int* in_sizes, int n_in,
                              void* d_out, int out_size, void* d_ws, size_t ws_size,
                              hipStream_t stream)
{
    const float* verts = (const float*)d_in[0];
    const int*   faces = (const int*)  d_in[1];
    const float* Km    = (const float*)d_in[2];
    const float* Rm    = (const float*)d_in[3];
    const float* tv    = (const float*)d_in[4];
    const float* dc    = (const float*)d_in[5];
    float* out = (float*)d_out;

    float4* pv  = (float4*)d_ws;          // NV float4   (64 KB)
    float4* tri = (float4*)d_ws + NV;     // NF*4 float4 (128 KB)

    proj_kernel <<<(NV + 255)/256, 256, 0, stream>>>(verts, Km, Rm, tv, dc, pv);
    setup_kernel<<<(NF + 255)/256, 256, 0, stream>>>(faces, pv, tri);
    raster_kernel<<<dim3(ISZ/TILE, ISZ/TILE), 256, 0, stream>>>(tri, out);
}

// Round 2
// 45.595 us; speedup vs baseline: 4.2557x; 4.2557x over previous
//
#include <hip/hip_runtime.h>

#define NV 4096
#define NF 2048
#define ISZ 256
#define OSZ 128
#define TILE 16
#define SLICES 8
#define CHUNK 256          // NF / SLICES
#define FAR_P 100.0f
#define NEAR_P 0.1f

// ---------------- kernel 1: per-face setup (projection fused) ----------------
// Global SoA:
//   e0[f] = (X0, Y0, X1, Y1)
//   e1[f] = (X2, Y2, RZ0, RZ1)
//   rz2[f]
//   bb[f] = (minx, maxx, miny, maxy)
__device__ __forceinline__ float3 project_one(
    const float* __restrict__ verts, int i,
    const float* __restrict__ Km, const float* __restrict__ Rm,
    const float* __restrict__ tv, const float* __restrict__ dc)
{
    float x = verts[3*i+0], y = verts[3*i+1], z = verts[3*i+2];
    float vx = x*Rm[0] + y*Rm[1] + z*Rm[2] + tv[0];
    float vy = x*Rm[3] + y*Rm[4] + z*Rm[5] + tv[1];
    float vz = x*Rm[6] + y*Rm[7] + z*Rm[8] + tv[2];
    float zd = vz + 1e-5f;
    float x_ = vx / zd;
    float y_ = vy / zd;
    float r2 = x_*x_ + y_*y_;
    float k1 = dc[0], k2 = dc[1], p1 = dc[2], p2 = dc[3], k3 = dc[4];
    float radial = 1.0f + k1*r2 + k2*r2*r2 + k3*r2*r2*r2;
    float x__ = x_*radial + 2.0f*p1*x_*y_ + p2*(r2 + 2.0f*x_*x_);
    float y__ = y_*radial + p1*(r2 + 2.0f*y_*y_) + 2.0f*p2*x_*y_;
    float u  = x__*Km[0] + y__*Km[1] + Km[2];
    float vv = x__*Km[3] + y__*Km[4] + Km[5];
    vv = 1024.0f - vv;
    u  = 2.0f*(u  - 512.0f) / 1024.0f;
    vv = 2.0f*(vv - 512.0f) / 1024.0f;
    return make_float3(u, vv, vz);
}

__global__ __launch_bounds__(256) void setup_kernel(
    const int* __restrict__ faces, const float* __restrict__ verts,
    const float* __restrict__ Km, const float* __restrict__ Rm,
    const float* __restrict__ tv, const float* __restrict__ dc,
    float4* __restrict__ e0, float4* __restrict__ e1,
    float* __restrict__ rz2, float4* __restrict__ bb)
{
    int f = blockIdx.x * 256 + threadIdx.x;
    if (f >= NF) return;
    float3 p0 = project_one(verts, faces[3*f+0], Km, Rm, tv, dc);
    float3 p1 = project_one(verts, faces[3*f+1], Km, Rm, tv, dc);
    float3 p2 = project_one(verts, faces[3*f+2], Km, Rm, tv, dc);
    float minx = fminf(p0.x, fminf(p1.x, p2.x)) - 1e-4f;
    float maxx = fmaxf(p0.x, fmaxf(p1.x, p2.x)) + 1e-4f;
    float miny = fminf(p0.y, fminf(p1.y, p2.y)) - 1e-4f;
    float maxy = fmaxf(p0.y, fmaxf(p1.y, p2.y)) + 1e-4f;
    e0[f]  = make_float4(p0.x, p0.y, p1.x, p1.y);
    e1[f]  = make_float4(p2.x, p2.y, 1.0f/p0.z, 1.0f/p1.z);
    rz2[f] = 1.0f/p2.z;
    bb[f]  = make_float4(minx, maxx, miny, maxy);
}

// ---------------- kernel 2: init z-buffer to FAR ----------------
__global__ __launch_bounds__(256) void init_kernel(int* __restrict__ zbuf)
{
    zbuf[blockIdx.x * 256 + threadIdx.x] = __float_as_int(FAR_P);
}

// ---------------- kernel 3: sliced tiled rasterizer ----------------
__global__ __launch_bounds__(256) void raster_kernel(
    const float4* __restrict__ e0, const float4* __restrict__ e1,
    const float* __restrict__ rz2, const float4* __restrict__ bb,
    int* __restrict__ zbuf)
{
    __shared__ float4 s_e0[CHUNK];
    __shared__ float4 s_e1[CHUNK];
    __shared__ float  s_rz2[CHUNK];
    __shared__ unsigned short s_list[CHUNK];
    __shared__ int s_cnt;

    const int tid  = threadIdx.x;
    const int bid  = blockIdx.x;
    const int slice = bid & (SLICES - 1);
    const int tileL = bid >> 3;
    const int tileX = tileL & 15, tileY = tileL >> 4;
    const int tx = tid & 15, ty = tid >> 4;
    const int px = tileX*TILE + tx, py = tileY*TILE + ty;

    const float xp = (2.0f*(float)px + 1.0f - 256.0f) * (1.0f/256.0f);
    const float yp = (2.0f*(float)(255 - py) + 1.0f - 256.0f) * (1.0f/256.0f);

    const float tbx0 = (2.0f*(float)(tileX*TILE)          + 1.0f - 256.0f) * (1.0f/256.0f);
    const float tbx1 = (2.0f*(float)(tileX*TILE + TILE-1) + 1.0f - 256.0f) * (1.0f/256.0f);
    const float tby1 = (2.0f*(float)(255 - tileY*TILE)           + 1.0f - 256.0f) * (1.0f/256.0f);
    const float tby0 = (2.0f*(float)(255 - (tileY*TILE+TILE-1))  + 1.0f - 256.0f) * (1.0f/256.0f);

    // stage this slice's chunk (SoA, coalesced), bbox test from registers
    const int f = slice*CHUNK + tid;
    float4 my_e0 = e0[f];
    float4 my_e1 = e1[f];
    float  my_rz = rz2[f];
    float4 my_bb = bb[f];
    s_e0[tid]  = my_e0;
    s_e1[tid]  = my_e1;
    s_rz2[tid] = my_rz;
    if (tid == 0) s_cnt = 0;
    __syncthreads();

    bool hit = (my_bb.x <= tbx1) && (my_bb.y >= tbx0) &&
               (my_bb.z <= tby1) && (my_bb.w >= tby0);
    const int lane = tid & 63;
    unsigned long long m = __ballot(hit);
    int wbase = 0;
    if (lane == 0 && m) wbase = atomicAdd(&s_cnt, (int)__popcll(m));
    wbase = __shfl(wbase, 0, 64);
    if (hit) {
        int pos = wbase + (int)__popcll(m & ((1ull << lane) - 1ull));
        s_list[pos] = (unsigned short)tid;
    }
    __syncthreads();

    const int cnt = s_cnt;
    float zmin = FAR_P;
    for (int k = 0; k < cnt; ++k) {
        int j = s_list[k];
        float4 q0 = s_e0[j];
        float4 q1 = s_e1[j];
        float  rz = s_rz2[j];
        // reference-exact edge functions
        float dx0 = q0.x - xp, dy0 = q0.y - yp;
        float dx1 = q0.z - xp, dy1 = q0.w - yp;
        float dx2 = q1.x - xp, dy2 = q1.y - yp;
        float w0 = dx1*dy2 - dx2*dy1;
        float w1 = dx2*dy0 - dx0*dy2;
        float w2 = dx0*dy1 - dx1*dy0;
        float area = (w0 + w1) + w2;
        bool  ok   = fabsf(area) > 1e-10f;
        float inv  = __builtin_amdgcn_rcpf(ok ? area : 1.0f);
        float b0 = w0*inv, b1 = w1*inv, b2 = w2*inv;
        bool inside = ok && (b0 >= 0.0f) && (b1 >= 0.0f) && (b2 >= 0.0f);
        float zinv = b0*q1.z + b1*q1.w + b2*rz;
        float zz = (fabsf(zinv) > 1e-10f) ? __builtin_amdgcn_rcpf(zinv) : 1.0f;
        bool valid = inside && (zz > NEAR_P) && (zz < FAR_P);
        zmin = fminf(zmin, valid ? zz : FAR_P);
    }

    if (zmin < FAR_P)
        atomicMin(&zbuf[py*ISZ + px], __float_as_int(zmin));
}

// ---------------- kernel 4: 2x2 AA downsample ----------------
__global__ __launch_bounds__(256) void down_kernel(
    const int* __restrict__ zbuf, float* __restrict__ out)
{
    int i = blockIdx.x * 256 + threadIdx.x;        // 0 .. 128*128-1
    int ox = i & (OSZ-1), oy = i >> 7;
    int base = (2*oy)*ISZ + 2*ox;
    float z00 = __int_as_float(zbuf[base]);
    float z01 = __int_as_float(zbuf[base + 1]);
    float z10 = __int_as_float(zbuf[base + ISZ]);
    float z11 = __int_as_float(zbuf[base + ISZ + 1]);
    out[i] = ((z00 + z01) + (z10 + z11)) * 0.25f;
}

extern "C" void kernel_launch(void* const* d_in, const int* in_sizes, int n_in,
                              void* d_out, int out_size, void* d_ws, size_t ws_size,
                              hipStream_t stream)
{
    const float* verts = (const float*)d_in[0];
    const int*   faces = (const int*)  d_in[1];
    const float* Km    = (const float*)d_in[2];
    const float* Rm    = (const float*)d_in[3];
    const float* tv    = (const float*)d_in[4];
    const float* dc    = (const float*)d_in[5];
    float* out = (float*)d_out;

    char* ws = (char*)d_ws;
    float4* e0  = (float4*)ws;                 ws += NF*sizeof(float4);
    float4* e1  = (float4*)ws;                 ws += NF*sizeof(float4);
    float4* bbx = (float4*)ws;                 ws += NF*sizeof(float4);
    float*  rz2 = (float*)ws;                  ws += NF*sizeof(float);
    int*    zbuf = (int*)ws;                   // ISZ*ISZ ints (256 KB)

    setup_kernel<<<(NF + 255)/256, 256, 0, stream>>>(faces, verts, Km, Rm, tv, dc,
                                                     e0, e1, rz2, bbx);
    init_kernel <<<(ISZ*ISZ)/256, 256, 0, stream>>>(zbuf);
    raster_kernel<<<(ISZ/TILE)*(ISZ/TILE)*SLICES, 256, 0, stream>>>(e0, e1, rz2, bbx, zbuf);
    down_kernel <<<(OSZ*OSZ)/256, 256, 0, stream>>>(zbuf, out);
}

// Round 3
// 39.181 us; speedup vs baseline: 4.9524x; 1.1637x over previous
//
#include <hip/hip_runtime.h>

#define NV 4096
#define NF 2048
#define ISZ 256
#define OSZ 128
#define TILE 16
#define SLICES 16
#define CHUNK 128          // NF / SLICES
#define FAR_P 100.0f
#define NEAR_P 0.1f

// ---------------- projection (fused into setup) ----------------
__device__ __forceinline__ float3 project_one(
    const float* __restrict__ verts, int i,
    const float* __restrict__ Km, const float* __restrict__ Rm,
    const float* __restrict__ tv, const float* __restrict__ dc)
{
    float x = verts[3*i+0], y = verts[3*i+1], z = verts[3*i+2];
    float vx = x*Rm[0] + y*Rm[1] + z*Rm[2] + tv[0];
    float vy = x*Rm[3] + y*Rm[4] + z*Rm[5] + tv[1];
    float vz = x*Rm[6] + y*Rm[7] + z*Rm[8] + tv[2];
    float zd = vz + 1e-5f;
    float x_ = vx / zd;
    float y_ = vy / zd;
    float r2 = x_*x_ + y_*y_;
    float k1 = dc[0], k2 = dc[1], p1 = dc[2], p2 = dc[3], k3 = dc[4];
    float radial = 1.0f + k1*r2 + k2*r2*r2 + k3*r2*r2*r2;
    float x__ = x_*radial + 2.0f*p1*x_*y_ + p2*(r2 + 2.0f*x_*x_);
    float y__ = y_*radial + p1*(r2 + 2.0f*y_*y_) + 2.0f*p2*x_*y_;
    float u  = x__*Km[0] + y__*Km[1] + Km[2];
    float vv = x__*Km[3] + y__*Km[4] + Km[5];
    vv = 1024.0f - vv;
    u  = 2.0f*(u  - 512.0f) / 1024.0f;
    vv = 2.0f*(vv - 512.0f) / 1024.0f;
    return make_float3(u, vv, vz);
}

// ---------------- kernel 1: setup faces + init zbuf (fused) ----------------
// grid = 256 blocks x 256 threads.
//   every block: writes 256 ints of zbuf = FAR
//   blocks 0..7: also project + set up face (bid*256+tid)
__global__ __launch_bounds__(256) void setup_kernel(
    const int* __restrict__ faces, const float* __restrict__ verts,
    const float* __restrict__ Km, const float* __restrict__ Rm,
    const float* __restrict__ tv, const float* __restrict__ dc,
    float4* __restrict__ e0, float4* __restrict__ e1,
    float* __restrict__ rz2, float4* __restrict__ bb,
    int* __restrict__ zbuf)
{
    const int tid = threadIdx.x, bid = blockIdx.x;
    zbuf[bid*256 + tid] = __float_as_int(FAR_P);
    if (bid >= NF/256) return;
    int f = bid*256 + tid;
    float3 p0 = project_one(verts, faces[3*f+0], Km, Rm, tv, dc);
    float3 p1 = project_one(verts, faces[3*f+1], Km, Rm, tv, dc);
    float3 p2 = project_one(verts, faces[3*f+2], Km, Rm, tv, dc);
    float minx = fminf(p0.x, fminf(p1.x, p2.x)) - 1e-4f;
    float maxx = fmaxf(p0.x, fmaxf(p1.x, p2.x)) + 1e-4f;
    float miny = fminf(p0.y, fminf(p1.y, p2.y)) - 1e-4f;
    float maxy = fmaxf(p0.y, fmaxf(p1.y, p2.y)) + 1e-4f;
    e0[f]  = make_float4(p0.x, p0.y, p1.x, p1.y);
    e1[f]  = make_float4(p2.x, p2.y, 1.0f/p0.z, 1.0f/p1.z);
    rz2[f] = 1.0f/p2.z;
    bb[f]  = make_float4(minx, maxx, miny, maxy);
}

// ---------------- kernel 2: sliced tiled rasterizer ----------------
// reference-exact edge/area arithmetic — do not reorder
#define EVAL(K, ZM) { \
    float4 q0 = s_e0[K]; float4 q1 = s_e1[K]; float rz = s_rz2[K]; \
    float dx0 = q0.x - xp, dy0 = q0.y - yp; \
    float dx1 = q0.z - xp, dy1 = q0.w - yp; \
    float dx2 = q1.x - xp, dy2 = q1.y - yp; \
    float w0 = dx1*dy2 - dx2*dy1; \
    float w1 = dx2*dy0 - dx0*dy2; \
    float w2 = dx0*dy1 - dx1*dy0; \
    float area = (w0 + w1) + w2; \
    bool ok = fabsf(area) > 1e-10f; \
    float inv = __builtin_amdgcn_rcpf(ok ? area : 1.0f); \
    float b0 = w0*inv, b1 = w1*inv, b2 = w2*inv; \
    bool inside = ok && (b0 >= 0.0f) && (b1 >= 0.0f) && (b2 >= 0.0f); \
    float zinv = b0*q1.z + b1*q1.w + b2*rz; \
    float zz = (fabsf(zinv) > 1e-10f) ? __builtin_amdgcn_rcpf(zinv) : 1.0f; \
    bool valid = inside && (zz > NEAR_P) && (zz < FAR_P); \
    ZM = fminf(ZM, valid ? zz : FAR_P); }

__global__ __launch_bounds__(256) void raster_kernel(
    const float4* __restrict__ e0, const float4* __restrict__ e1,
    const float* __restrict__ rz2, const float4* __restrict__ bb,
    int* __restrict__ zbuf)
{
    __shared__ float4 s_e0[CHUNK];
    __shared__ float4 s_e1[CHUNK];
    __shared__ float  s_rz2[CHUNK];
    __shared__ unsigned short s_list[CHUNK];
    __shared__ int s_cnt;

    const int tid  = threadIdx.x;
    const int bid  = blockIdx.x;
    const int slice = bid & (SLICES - 1);
    const int tileL = bid >> 4;
    const int tileX = tileL & 15, tileY = tileL >> 4;
    const int tx = tid & 15, ty = tid >> 4;
    const int px = tileX*TILE + tx, py = tileY*TILE + ty;

    const float xp = (2.0f*(float)px + 1.0f - 256.0f) * (1.0f/256.0f);
    const float yp = (2.0f*(float)(255 - py) + 1.0f - 256.0f) * (1.0f/256.0f);

    const float tbx0 = (2.0f*(float)(tileX*TILE)          + 1.0f - 256.0f) * (1.0f/256.0f);
    const float tbx1 = (2.0f*(float)(tileX*TILE + TILE-1) + 1.0f - 256.0f) * (1.0f/256.0f);
    const float tby1 = (2.0f*(float)(255 - tileY*TILE)           + 1.0f - 256.0f) * (1.0f/256.0f);
    const float tby0 = (2.0f*(float)(255 - (tileY*TILE+TILE-1))  + 1.0f - 256.0f) * (1.0f/256.0f);

    const int fbase = slice*CHUNK;
    if (tid == 0) s_cnt = 0;
    __syncthreads();

    // phase 1: bbox-only load + cull + compact
    bool hit = false;
    if (tid < CHUNK) {
        float4 my_bb = bb[fbase + tid];
        hit = (my_bb.x <= tbx1) && (my_bb.y >= tbx0) &&
              (my_bb.z <= tby1) && (my_bb.w >= tby0);
    }
    const int lane = tid & 63;
    unsigned long long m = __ballot(hit);
    int wbase = 0;
    if (lane == 0 && m) wbase = atomicAdd(&s_cnt, (int)__popcll(m));
    wbase = __shfl(wbase, 0, 64);
    if (hit) {
        int pos = wbase + (int)__popcll(m & ((1ull << lane) - 1ull));
        s_list[pos] = (unsigned short)tid;
    }
    __syncthreads();

    const int cnt = s_cnt;
    if (cnt == 0) return;

    // phase 2: gather-stage only survivors (compacted)
    if (tid < cnt) {
        int j = fbase + s_list[tid];
        s_e0[tid]  = e0[j];
        s_e1[tid]  = e1[j];
        s_rz2[tid] = rz2[j];
    }
    __syncthreads();

    // phase 3: per-pixel eval, 2x unrolled with independent accumulators
    float zmin0 = FAR_P, zmin1 = FAR_P;
    int k = 0;
    for (; k + 2 <= cnt; k += 2) {
        EVAL(k,   zmin0);
        EVAL(k+1, zmin1);
    }
    if (k < cnt) EVAL(k, zmin0);
    float zmin = fminf(zmin0, zmin1);

    if (zmin < FAR_P)
        atomicMin(&zbuf[py*ISZ + px], __float_as_int(zmin));
}

// ---------------- kernel 3: 2x2 AA downsample ----------------
__global__ __launch_bounds__(256) void down_kernel(
    const int* __restrict__ zbuf, float* __restrict__ out)
{
    int i = blockIdx.x * 256 + threadIdx.x;        // 0 .. 128*128-1
    int ox = i & (OSZ-1), oy = i >> 7;
    int base = (2*oy)*ISZ + 2*ox;
    float z00 = __int_as_float(zbuf[base]);
    float z01 = __int_as_float(zbuf[base + 1]);
    float z10 = __int_as_float(zbuf[base + ISZ]);
    float z11 = __int_as_float(zbuf[base + ISZ + 1]);
    out[i] = ((z00 + z01) + (z10 + z11)) * 0.25f;
}

extern "C" void kernel_launch(void* const* d_in, const int* in_sizes, int n_in,
                              void* d_out, int out_size, void* d_ws, size_t ws_size,
                              hipStream_t stream)
{
    const float* verts = (const float*)d_in[0];
    const int*   faces = (const int*)  d_in[1];
    const float* Km    = (const float*)d_in[2];
    const float* Rm    = (const float*)d_in[3];
    const float* tv    = (const float*)d_in[4];
    const float* dc    = (const float*)d_in[5];
    float* out = (float*)d_out;

    char* ws = (char*)d_ws;
    float4* e0  = (float4*)ws;                 ws += NF*sizeof(float4);
    float4* e1  = (float4*)ws;                 ws += NF*sizeof(float4);
    float4* bbx = (float4*)ws;                 ws += NF*sizeof(float4);
    float*  rz2 = (float*)ws;                  ws += NF*sizeof(float);
    int*    zbuf = (int*)ws;                   // ISZ*ISZ ints (256 KB)

    setup_kernel<<<(ISZ*ISZ)/256, 256, 0, stream>>>(faces, verts, Km, Rm, tv, dc,
                                                    e0, e1, rz2, bbx, zbuf);
    raster_kernel<<<(ISZ/TILE)*(ISZ/TILE)*SLICES, 256, 0, stream>>>(e0, e1, rz2, bbx, zbuf);
    down_kernel <<<(OSZ*OSZ)/256, 256, 0, stream>>>(zbuf, out);
}